// Round 4
// baseline (62.645 us; speedup 1.0000x reference)
//
#include <hip/hip_runtime.h>

// Flattened state index: idx = b0*8 + b1*4 + b2*2 + b3  (qubit q -> bit (3-q))
template<int Q>
__device__ __forceinline__ void apply_ry(float (&sr)[16], float (&si)[16], float c, float s) {
    constexpr int m = 1 << (3 - Q);
    #pragma unroll
    for (int idx = 0; idx < 16; ++idx) {
        if (!(idx & m)) {
            const int j = idx | m;
            float ar = sr[idx], ai = si[idx], br = sr[j], bi = si[j];
            sr[idx] = c * ar - s * br;  si[idx] = c * ai - s * bi;
            sr[j]   = s * ar + c * br;  si[j]   = s * ai + c * bi;
        }
    }
}
// RZ(theta): bit==0 amp *= (c - i s), bit==1 amp *= (c + i s)   [c,s of theta/2]
template<int Q>
__device__ __forceinline__ void apply_rz(float (&sr)[16], float (&si)[16], float c, float s) {
    constexpr int m = 1 << (3 - Q);
    #pragma unroll
    for (int idx = 0; idx < 16; ++idx) {
        float r = sr[idx], i_ = si[idx];
        if (idx & m) { sr[idx] = c * r - s * i_;  si[idx] = c * i_ + s * r; }
        else         { sr[idx] = c * r + s * i_;  si[idx] = c * i_ - s * r; }
    }
}
template<int C, int T>
__device__ __forceinline__ void apply_cnot(float (&sr)[16], float (&si)[16]) {
    constexpr int mc = 1 << (3 - C), mt = 1 << (3 - T);
    #pragma unroll
    for (int idx = 0; idx < 16; ++idx) {
        if ((idx & mc) && !(idx & mt)) {
            const int j = idx | mt;
            float tr = sr[idx], ti = si[idx];
            sr[idx] = sr[j];  si[idx] = si[j];
            sr[j] = tr;       si[j] = ti;
        }
    }
}

struct Uni {                     // batch-uniform trig (computed once per thread)
    float th0[4];                // layer-1 RY param angles (merged with x)
    float cf[4], sf[4];          // layer-1 RZ FULL angle (global phase dropped)
    float c1y[4], s1y[4];        // layer-2 RY half-angle
    float c1z[4], s1z[4];        // layer-2 RZ half-angle
    float c2y[4], s2y[4];        // layer-3 RY half-angle (layer-3 RZ unobservable)
};

__device__ __forceinline__ float4 run_circuit(const Uni& u, float4 xr) {
    // ---- layer 1: RY(x_i + theta) merged with encoding; RZ as per-qubit phase ----
    float cy[4], sy[4];
    __sincosf(0.5f * (xr.x + u.th0[0]), &sy[0], &cy[0]);
    __sincosf(0.5f * (xr.y + u.th0[1]), &sy[1], &cy[1]);
    __sincosf(0.5f * (xr.z + u.th0[2]), &sy[2], &cy[2]);
    __sincosf(0.5f * (xr.w + u.th0[3]), &sy[3], &cy[3]);
    float v1r[4], v1i[4];
    #pragma unroll
    for (int i = 0; i < 4; ++i) { v1r[i] = sy[i] * u.cf[i]; v1i[i] = sy[i] * u.sf[i]; }

    // pair tensor products (component 0 of each qubit real)
    float pr[4], pi_[4], qr[4], qi[4];
    pr[0] = cy[0] * cy[1];                          pi_[0] = 0.0f;
    pr[1] = cy[0] * v1r[1];                         pi_[1] = cy[0] * v1i[1];
    pr[2] = v1r[0] * cy[1];                         pi_[2] = v1i[0] * cy[1];
    pr[3] = v1r[0] * v1r[1] - v1i[0] * v1i[1];      pi_[3] = v1r[0] * v1i[1] + v1i[0] * v1r[1];
    qr[0] = cy[2] * cy[3];                          qi[0] = 0.0f;
    qr[1] = cy[2] * v1r[3];                         qi[1] = cy[2] * v1i[3];
    qr[2] = v1r[2] * cy[3];                         qi[2] = v1i[2] * cy[3];
    qr[3] = v1r[2] * v1r[3] - v1i[2] * v1i[3];      qi[3] = v1r[2] * v1i[3] + v1i[2] * v1r[3];

    float sr[16], si[16];
    #pragma unroll
    for (int p = 0; p < 4; ++p)
        #pragma unroll
        for (int q = 0; q < 4; ++q) {
            sr[p * 4 + q] = pr[p] * qr[q] - pi_[p] * qi[q];
            si[p * 4 + q] = pr[p] * qi[q] + pi_[p] * qr[q];
        }

    apply_cnot<0, 1>(sr, si);
    apply_cnot<1, 2>(sr, si);
    apply_cnot<2, 3>(sr, si);

    // ---- layer 2: RY + RZ, CNOT chain ----
    apply_ry<0>(sr, si, u.c1y[0], u.s1y[0]);  apply_rz<0>(sr, si, u.c1z[0], u.s1z[0]);
    apply_ry<1>(sr, si, u.c1y[1], u.s1y[1]);  apply_rz<1>(sr, si, u.c1z[1], u.s1z[1]);
    apply_ry<2>(sr, si, u.c1y[2], u.s1y[2]);  apply_rz<2>(sr, si, u.c1z[2], u.s1z[2]);
    apply_ry<3>(sr, si, u.c1y[3], u.s1y[3]);  apply_rz<3>(sr, si, u.c1z[3], u.s1z[3]);
    apply_cnot<0, 1>(sr, si);
    apply_cnot<1, 2>(sr, si);
    apply_cnot<2, 3>(sr, si);

    // ---- layer 3: RY only (RZ unobservable), CNOT chain ----
    apply_ry<0>(sr, si, u.c2y[0], u.s2y[0]);
    apply_ry<1>(sr, si, u.c2y[1], u.s2y[1]);
    apply_ry<2>(sr, si, u.c2y[2], u.s2y[2]);
    apply_ry<3>(sr, si, u.c2y[3], u.s2y[3]);
    apply_cnot<0, 1>(sr, si);
    apply_cnot<1, 2>(sr, si);
    apply_cnot<2, 3>(sr, si);

    // ---- <Z_q> via tree-structured signed sums ----
    float p16[16];
    #pragma unroll
    for (int i = 0; i < 16; ++i) p16[i] = sr[i] * sr[i] + si[i] * si[i];
    float s8[8], d8[8];
    #pragma unroll
    for (int i = 0; i < 8; ++i) { s8[i] = p16[2 * i] + p16[2 * i + 1];
                                  d8[i] = p16[2 * i] - p16[2 * i + 1]; }
    float z3 = (d8[0] + d8[1]) + (d8[2] + d8[3]) + ((d8[4] + d8[5]) + (d8[6] + d8[7]));
    float z2 = (s8[0] - s8[1]) + (s8[2] - s8[3]) + ((s8[4] - s8[5]) + (s8[6] - s8[7]));
    float t4[4];
    #pragma unroll
    for (int i = 0; i < 4; ++i) t4[i] = s8[2 * i] + s8[2 * i + 1];
    float z1 = (t4[0] - t4[1]) + (t4[2] - t4[3]);
    float z0 = (t4[0] + t4[1]) - (t4[2] + t4[3]);

    float4 o;  o.x = z0;  o.y = z1;  o.z = z2;  o.w = z3;
    return o;
}

// 2 batch elements per thread: amortizes uniform trig, doubles independent
// FMA streams (ILP) to cover the CPI gap at low waves/SIMD.
__global__ __launch_bounds__(256) void qsim_kernel(const float* __restrict__ x,
                                                   const float* __restrict__ params,
                                                   float* __restrict__ out, int n) {
    int t = blockIdx.x * blockDim.x + threadIdx.x;
    int half = n >> 1;
    if (t >= half) return;

    // ---- uniform trig (batch-independent; params[l*12 + i*3 + {0:ry,1:rz}]) ----
    Uni u;
    #pragma unroll
    for (int i = 0; i < 4; ++i) {
        u.th0[i] = params[0 * 12 + i * 3 + 0];
        __sincosf(params[0 * 12 + i * 3 + 1],        &u.sf[i],  &u.cf[i]);
        __sincosf(0.5f * params[1 * 12 + i * 3 + 0], &u.s1y[i], &u.c1y[i]);
        __sincosf(0.5f * params[1 * 12 + i * 3 + 1], &u.s1z[i], &u.c1z[i]);
        __sincosf(0.5f * params[2 * 12 + i * 3 + 0], &u.s2y[i], &u.c2y[i]);
    }

    float4 xa = reinterpret_cast<const float4*>(x)[t];
    float4 xb = reinterpret_cast<const float4*>(x)[t + half];

    float4 oa = run_circuit(u, xa);
    float4 ob = run_circuit(u, xb);

    reinterpret_cast<float4*>(out)[t]        = oa;
    reinterpret_cast<float4*>(out)[t + half] = ob;
}

extern "C" void kernel_launch(void* const* d_in, const int* in_sizes, int n_in,
                              void* d_out, int out_size, void* d_ws, size_t ws_size,
                              hipStream_t stream) {
    const float* x      = (const float*)d_in[0];   // (B,4) f32
    const float* params = (const float*)d_in[1];   // (3,4,3) f32
    float* out          = (float*)d_out;           // (B,4) f32
    int n = in_sizes[0] / 4;
    int threads = n / 2;
    int blocks = (threads + 255) / 256;
    hipLaunchKernelGGL(qsim_kernel, dim3(blocks), dim3(256), 0, stream, x, params, out, n);
}

// Round 5
// 62.532 us; speedup vs baseline: 1.0018x; 1.0018x over previous
//
#include <hip/hip_runtime.h>

// Flattened state index: idx = b0*8 + b1*4 + b2*2 + b3  (qubit q -> bit (3-q))
template<int Q>
__device__ __forceinline__ void apply_ry(float (&sr)[16], float (&si)[16], float c, float s) {
    constexpr int m = 1 << (3 - Q);
    #pragma unroll
    for (int idx = 0; idx < 16; ++idx) {
        if (!(idx & m)) {
            const int j = idx | m;
            float ar = sr[idx], ai = si[idx], br = sr[j], bi = si[j];
            sr[idx] = c * ar - s * br;  si[idx] = c * ai - s * bi;
            sr[j]   = s * ar + c * br;  si[j]   = s * ai + c * bi;
        }
    }
}
// RZ(theta): bit==0 amp *= (c - i s), bit==1 amp *= (c + i s)   [c,s of theta/2]
template<int Q>
__device__ __forceinline__ void apply_rz(float (&sr)[16], float (&si)[16], float c, float s) {
    constexpr int m = 1 << (3 - Q);
    #pragma unroll
    for (int idx = 0; idx < 16; ++idx) {
        float r = sr[idx], i_ = si[idx];
        if (idx & m) { sr[idx] = c * r - s * i_;  si[idx] = c * i_ + s * r; }
        else         { sr[idx] = c * r + s * i_;  si[idx] = c * i_ - s * r; }
    }
}
template<int C, int T>
__device__ __forceinline__ void apply_cnot(float (&sr)[16], float (&si)[16]) {
    constexpr int mc = 1 << (3 - C), mt = 1 << (3 - T);
    #pragma unroll
    for (int idx = 0; idx < 16; ++idx) {
        if ((idx & mc) && !(idx & mt)) {
            const int j = idx | mt;
            float tr = sr[idx], ti = si[idx];
            sr[idx] = sr[j];  si[idx] = si[j];
            sr[j] = tr;       si[j] = ti;
        }
    }
}

// 1 element/thread, (256,4): <=128 VGPR so all 4 waves/SIMD are co-resident.
__global__ __launch_bounds__(256, 4) void qsim_kernel(const float* __restrict__ x,
                                                      const float* __restrict__ params,
                                                      float* __restrict__ out, int n) {
    int b = blockIdx.x * blockDim.x + threadIdx.x;
    if (b >= n) return;

    // ---- params as 9 coalesced float4 loads (36 floats; [l*12 + i*3 + {0:ry,1:rz,2:-}]) ----
    float pm[36];
    #pragma unroll
    for (int i = 0; i < 9; ++i) {
        float4 v = reinterpret_cast<const float4*>(params)[i];
        pm[4 * i + 0] = v.x;  pm[4 * i + 1] = v.y;  pm[4 * i + 2] = v.z;  pm[4 * i + 3] = v.w;
    }

    // ---- uniform trig (batch-independent), native trans ops ----
    float cf[4], sf[4];          // layer-1 RZ FULL angle (global phase dropped)
    float c1y[4], s1y[4];        // layer-2 RY half-angle
    float c1z[4], s1z[4];        // layer-2 RZ half-angle
    float c2y[4], s2y[4];        // layer-3 RY half-angle (layer-3 RZ unobservable)
    #pragma unroll
    for (int i = 0; i < 4; ++i) {
        float a0 = pm[i * 3 + 1];                 // layer-1 rz (full)
        float a1 = 0.5f * pm[12 + i * 3 + 0];     // layer-2 ry
        float a2 = 0.5f * pm[12 + i * 3 + 1];     // layer-2 rz
        float a3 = 0.5f * pm[24 + i * 3 + 0];     // layer-3 ry
        sf[i]  = __sinf(a0);  cf[i]  = __cosf(a0);
        s1y[i] = __sinf(a1);  c1y[i] = __cosf(a1);
        s1z[i] = __sinf(a2);  c1z[i] = __cosf(a2);
        s2y[i] = __sinf(a3);  c2y[i] = __cosf(a3);
    }

    // ---- layer 1: RY(x_i + theta) merged with encoding; RZ as per-qubit phase ----
    float4 xr = reinterpret_cast<const float4*>(x)[b];
    float cy[4], sy[4];
    {
        float a0 = 0.5f * (xr.x + pm[0]);
        float a1 = 0.5f * (xr.y + pm[3]);
        float a2 = 0.5f * (xr.z + pm[6]);
        float a3 = 0.5f * (xr.w + pm[9]);
        sy[0] = __sinf(a0);  cy[0] = __cosf(a0);
        sy[1] = __sinf(a1);  cy[1] = __cosf(a1);
        sy[2] = __sinf(a2);  cy[2] = __cosf(a2);
        sy[3] = __sinf(a3);  cy[3] = __cosf(a3);
    }
    float v1r[4], v1i[4];
    #pragma unroll
    for (int i = 0; i < 4; ++i) { v1r[i] = sy[i] * cf[i]; v1i[i] = sy[i] * sf[i]; }

    // pair tensor products (component 0 of each qubit real)
    float pr[4], pi_[4], qr[4], qi[4];
    pr[0] = cy[0] * cy[1];                          pi_[0] = 0.0f;
    pr[1] = cy[0] * v1r[1];                         pi_[1] = cy[0] * v1i[1];
    pr[2] = v1r[0] * cy[1];                         pi_[2] = v1i[0] * cy[1];
    pr[3] = v1r[0] * v1r[1] - v1i[0] * v1i[1];      pi_[3] = v1r[0] * v1i[1] + v1i[0] * v1r[1];
    qr[0] = cy[2] * cy[3];                          qi[0] = 0.0f;
    qr[1] = cy[2] * v1r[3];                         qi[1] = cy[2] * v1i[3];
    qr[2] = v1r[2] * cy[3];                         qi[2] = v1i[2] * cy[3];
    qr[3] = v1r[2] * v1r[3] - v1i[2] * v1i[3];      qi[3] = v1r[2] * v1i[3] + v1i[2] * v1r[3];

    float sr[16], si[16];
    #pragma unroll
    for (int p = 0; p < 4; ++p)
        #pragma unroll
        for (int q = 0; q < 4; ++q) {
            sr[p * 4 + q] = pr[p] * qr[q] - pi_[p] * qi[q];
            si[p * 4 + q] = pr[p] * qi[q] + pi_[p] * qr[q];
        }

    apply_cnot<0, 1>(sr, si);
    apply_cnot<1, 2>(sr, si);
    apply_cnot<2, 3>(sr, si);

    // ---- layer 2: RY + RZ, CNOT chain ----
    apply_ry<0>(sr, si, c1y[0], s1y[0]);  apply_rz<0>(sr, si, c1z[0], s1z[0]);
    apply_ry<1>(sr, si, c1y[1], s1y[1]);  apply_rz<1>(sr, si, c1z[1], s1z[1]);
    apply_ry<2>(sr, si, c1y[2], s1y[2]);  apply_rz<2>(sr, si, c1z[2], s1z[2]);
    apply_ry<3>(sr, si, c1y[3], s1y[3]);  apply_rz<3>(sr, si, c1z[3], s1z[3]);
    apply_cnot<0, 1>(sr, si);
    apply_cnot<1, 2>(sr, si);
    apply_cnot<2, 3>(sr, si);

    // ---- layer 3: RY only (RZ unobservable), CNOT chain ----
    apply_ry<0>(sr, si, c2y[0], s2y[0]);
    apply_ry<1>(sr, si, c2y[1], s2y[1]);
    apply_ry<2>(sr, si, c2y[2], s2y[2]);
    apply_ry<3>(sr, si, c2y[3], s2y[3]);
    apply_cnot<0, 1>(sr, si);
    apply_cnot<1, 2>(sr, si);
    apply_cnot<2, 3>(sr, si);

    // ---- <Z_q> via tree-structured signed sums ----
    float p16[16];
    #pragma unroll
    for (int i = 0; i < 16; ++i) p16[i] = sr[i] * sr[i] + si[i] * si[i];
    float s8[8], d8[8];
    #pragma unroll
    for (int i = 0; i < 8; ++i) { s8[i] = p16[2 * i] + p16[2 * i + 1];
                                  d8[i] = p16[2 * i] - p16[2 * i + 1]; }
    float z3 = (d8[0] + d8[1]) + (d8[2] + d8[3]) + ((d8[4] + d8[5]) + (d8[6] + d8[7]));
    float z2 = (s8[0] - s8[1]) + (s8[2] - s8[3]) + ((s8[4] - s8[5]) + (s8[6] - s8[7]));
    float t4[4];
    #pragma unroll
    for (int i = 0; i < 4; ++i) t4[i] = s8[2 * i] + s8[2 * i + 1];
    float z1 = (t4[0] - t4[1]) + (t4[2] - t4[3]);
    float z0 = (t4[0] + t4[1]) - (t4[2] + t4[3]);

    float4 o;  o.x = z0;  o.y = z1;  o.z = z2;  o.w = z3;
    reinterpret_cast<float4*>(out)[b] = o;
}

extern "C" void kernel_launch(void* const* d_in, const int* in_sizes, int n_in,
                              void* d_out, int out_size, void* d_ws, size_t ws_size,
                              hipStream_t stream) {
    const float* x      = (const float*)d_in[0];   // (B,4) f32
    const float* params = (const float*)d_in[1];   // (3,4,3) f32
    float* out          = (float*)d_out;           // (B,4) f32
    int n = in_sizes[0] / 4;
    int blocks = (n + 255) / 256;
    hipLaunchKernelGGL(qsim_kernel, dim3(blocks), dim3(256), 0, stream, x, params, out, n);
}